// Round 5
// baseline (116.438 us; speedup 1.0000x reference)
//
#include <hip/hip_runtime.h>

#define BSZ   2
#define NBOX  6300
#define NATTR 85
#define NCLS  80
#define CAP   256      // per-(img,class) cap; count ~ Binom(6300,1/160): mean 39, sd 6.3
#define TPB   512
#define GRP   (TPB / 4)   // 128 4-lane groups per block

typedef unsigned long long ull;

static __device__ __forceinline__ ull mask_for(int rem) {
  if (rem <= 0) return 0ull;
  if (rem >= 64) return ~0ull;
  return (1ull << rem) - 1ull;
}

// ONE kernel, one block per (img, cls). No workspace, no second node (R4 showed
// node 2 costs ~13 us), no grid barrier (R3: ~43-65 us however implemented).
//
// R2 post-mortem: its 58.8-us scan was TA-bound -- 85 scalar loads/box with
// 340-B lane stride = 64 distinct lines per wave-load. Fix here:
//   * 4 lanes per box, lane gl loads dwords attr = gl + 4j  (one vector base +
//     20 immediate-offset loads, coalesced in 4-lane runs)
//   * conf early-out: load attrs 0..7 first, broadcast obj within the group;
//     if obj <= 0.5 (P=0.5 on this data) the box's owner is class 0 and its 80
//     scores are irrelevant -> skip the 20 score loads (masked lanes issue no
//     TA transactions). Halves lines touched.
//   * XCD-bijective block mapping: assuming round-robin bid%8 -> XCD, all
//     blocks on one XCD get the SAME image (2.14 MB < 4 MB per-XCD L2).
//     Mapping is bijective over (img,cls); if the XCD assignment differs it
//     only affects speed, not correctness.
//
// Ref semantics per box (R2-verified, absmax 0):
//   conf = obj > 0.5; masked scores = conf ? scores : 0
//   cls_idx = argmax(masked scores)  (first-index tiebreak; all-zero -> 0)
//   valid = conf && max_score > 0.3
// Block owns every box with cls_idx == its class; owners write zero rows for
// invalid boxes, push valid ones to an LDS list (order-independent: NMS rank
// is the stable total order (obj desc, box idx asc)), then greedy per-class
// NMS == the ref's global greedy loop restricted to this class. Every output
// row is written exactly once by its unique owner.
__global__ __launch_bounds__(TPB) void nms_fused(
    const float* __restrict__ x,
    float* __restrict__ out) {
  __shared__ int   scnt;
  __shared__ float sx1[CAP], sy1[CAP], sx2[CAP], sy2[CAP];
  __shared__ float sob[CAP], smx[CAP];
  __shared__ int   sbi[CAP];
  // fallback-only (k > 64), rank-ordered
  __shared__ float px1[CAP], py1[CAP], px2[CAP], py2[CAP];
  __shared__ float pob[CAP], pmx[CAP];
  __shared__ int   pbi[CAP];

  int bid  = blockIdx.x;
  // XCD-bijective mapping: residue r8 = bid%8 -> XCD; r8<4 -> img0, else img1.
  int r8   = bid & 7;
  int img  = (r8 < 4) ? 0 : 1;
  int cls  = (r8 & 3) * 20 + (bid >> 3);   // bijective over 0..79 per image
  int t    = threadIdx.x;
  int lane = t & 63;
  int w    = t >> 6;
  int gl   = t & 3;        // lane within 4-lane group
  int gb   = t >> 2;       // group id within block, 0..127
  int gbase = lane & ~3;   // wave-lane index of the group's lane 0

  if (t == 0) scnt = 0;
  __syncthreads();

  const float* xb = x + (long)img * NBOX * NATTR;
  float*       ob = out + (long)img * NBOX * 8;

  // ---- scan: 4-lane-per-box cooperative, conf early-out ----
  for (int b = gb; b < NBOX; b += GRP) {
    const float* p = xb + (long)b * NATTR;
    float v0 = p[gl];        // attrs 0..3  (cx, cy, w, h across the group)
    float v1 = p[gl + 4];    // attrs 4..7  (lane 0 holds obj)
    float obj = __shfl(v1, gbase);
    bool conf = obj > 0.5f;

    if (conf) {
      // per-lane local argmax over its score attrs (ascending attr order ->
      // strict > keeps first index, matching jnp.argmax)
      float lv = -1.0f;
      int   la = NATTR;
      if (gl + 4 >= 5) { lv = v1; la = gl + 4; }   // attrs 5..7
#pragma unroll
      for (int j = 2; j < 22; ++j) {
        int a = gl + 4 * j;                        // attrs 8..87
        if (a < NATTR) {
          float s = p[a];                          // base + imm offset load
          if (s > lv) { lv = s; la = a; }
        }
      }
      // 2-step group reduce, first-index tiebreak
#pragma unroll
      for (int off = 1; off <= 2; off <<= 1) {
        float ov = __shfl_xor(lv, off);
        int   oa = __shfl_xor(la, off);
        if (ov > lv || (ov == lv && oa < la)) { lv = ov; la = oa; }
      }
      int  ci    = la - 5;
      bool valid = lv > 0.3f;

      if (ci == cls) {                 // group-uniform branch
        // gather coords to all group lanes (shfl needs the sources active)
        float cx = __shfl(v0, gbase);
        float cy = __shfl(v0, gbase + 1);
        float ww = __shfl(v0, gbase + 2);
        float hh = __shfl(v0, gbase + 3);
        if (gl == 0) {
          if (valid) {
            int slot = atomicAdd(&scnt, 1);   // LDS atomic, ~39 pushes/block
            if (slot < CAP) {
              float hw = ww * 0.5f, hh2 = hh * 0.5f;  // exact halving; fma-safe
              sx1[slot] = cx - hw;  sy1[slot] = cy - hh2;
              sx2[slot] = cx + hw;  sy2[slot] = cy + hh2;
              sob[slot] = obj;      smx[slot] = lv;
              sbi[slot] = b;
            }
          } else {
            float4 z = make_float4(0.f, 0.f, 0.f, 0.f);
            float4* o = (float4*)(ob + (long)b * 8);
            o[0] = z; o[1] = z;
          }
        }
      }
    } else if (cls == 0 && gl == 0) {
      // conf-fail: masked scores all zero -> argmax = 0 -> class-0 block owns
      float4 z = make_float4(0.f, 0.f, 0.f, 0.f);
      float4* o = (float4*)(ob + (long)b * 8);
      o[0] = z; o[1] = z;
    }
  }
  __syncthreads();

  int k = scnt < CAP ? scnt : CAP;
  if (k == 0) return;                  // uniform

  if (k <= 64) {
    // ================== register fast path (wave 0 only) ==================
    if (w == 0) {
      int j = lane;
      float x1 = 0.f, y1 = 0.f, x2 = 0.f, y2 = 0.f, sc = 0.f, mx = 0.f;
      int bi = 0;
      if (j < k) {
        x1 = sx1[j]; y1 = sy1[j]; x2 = sx2[j]; y2 = sy2[j];
        sc = sob[j]; mx = smx[j]; bi = sbi[j];
      }
      // rank = stable argsort(-obj, tiebreak: box index asc) -- independent of
      // the atomicAdd arrival order. All 64 lanes run the loop (no divergence);
      // j>=k lanes get identity rank j (>= k, no collision: sc=0 there).
      int rank = 0;
      for (int i = 0; i < k; i++) {
        float si  = __shfl(sc, i);
        int   bii = __shfl(bi, i);
        rank += (si > sc) || (si == sc && bii < bi);
      }
      if (j >= k) rank = j;

      // scatter to rank order: after this, lane index == rank.
      int r4 = rank << 2;
      x1 = __int_as_float(__builtin_amdgcn_ds_permute(r4, __float_as_int(x1)));
      y1 = __int_as_float(__builtin_amdgcn_ds_permute(r4, __float_as_int(y1)));
      x2 = __int_as_float(__builtin_amdgcn_ds_permute(r4, __float_as_int(x2)));
      y2 = __int_as_float(__builtin_amdgcn_ds_permute(r4, __float_as_int(y2)));
      sc = __int_as_float(__builtin_amdgcn_ds_permute(r4, __float_as_int(sc)));
      mx = __int_as_float(__builtin_amdgcn_ds_permute(r4, __float_as_int(mx)));
      bi = __builtin_amdgcn_ds_permute(r4, bi);

      float ar = (x2 - x1) * (y2 - y1);   // ref area expression

      // greedy: kept rank r suppresses later ranks with IoU >= 0.4
      ull keep = mask_for(k);
      for (int r = 0; r < k - 1; r++) {
        if (!((keep >> r) & 1ull)) continue;   // uniform skip
        float X1 = __shfl(x1, r), Y1 = __shfl(y1, r);
        float X2 = __shfl(x2, r), Y2 = __shfl(y2, r);
        float AR = __shfl(ar, r);
        float iw = fminf(X2, x2) - fmaxf(X1, x1);
        float ih = fminf(Y2, y2) - fmaxf(Y1, y1);
        iw = fmaxf(iw, 0.0f); ih = fmaxf(ih, 0.0f);
        float inter = iw * ih;
        float iou = inter / (AR + ar - inter + 1e-16f);  // ref assoc + eps
        keep &= ~__ballot(iou >= 0.4f && lane > r);
      }

      if (lane < k) {
        float4 a, b4;
        if ((keep >> lane) & 1ull) {
          a  = make_float4((float)img, x1, y1, x2);
          b4 = make_float4(y2, sc, mx, (float)cls);
        } else {
          a  = make_float4(0.f, 0.f, 0.f, 0.f);
          b4 = a;
        }
        float4* o = (float4*)(ob + (long)bi * 8);
        o[0] = a; o[1] = b4;
      }
    }
    return;
  }

  // ====================== generic LDS fallback (k > 64) ======================
  if (t < k) {
    float bx1 = sx1[t], by1 = sy1[t], bx2 = sx2[t], by2 = sy2[t];
    float bob = sob[t], bmx = smx[t];
    int   bidx = sbi[t];
    int rank = 0;
    for (int j2 = 0; j2 < k; j2++) {
      float sj = sob[j2];
      rank += (sj > bob) || (sj == bob && sbi[j2] < bidx);
    }
    px1[rank] = bx1; py1[rank] = by1;
    px2[rank] = bx2; py2[rank] = by2;
    pob[rank] = bob; pmx[rank] = bmx;
    pbi[rank] = bidx;
  }
  __syncthreads();

  if (w == 0) {
    float mx1[4], my1[4], mx2[4], my2[4], mar[4], mob[4], mmx[4];
    int   mbi[4];
#pragma unroll
    for (int s = 0; s < 4; s++) {
      int e = s * 64 + lane;
      if (e < k) {
        mx1[s] = px1[e]; my1[s] = py1[e];
        mx2[s] = px2[e]; my2[s] = py2[e];
        mob[s] = pob[e]; mmx[s] = pmx[e];
        mbi[s] = pbi[e];
        mar[s] = (mx2[s] - mx1[s]) * (my2[s] - my1[s]);
      } else {
        mx1[s] = 0; my1[s] = 0; mx2[s] = 0; my2[s] = 0;
        mar[s] = 0; mob[s] = 0; mmx[s] = 0; mbi[s] = 0;
      }
    }
    ull km0 = mask_for(k);
    ull km1 = mask_for(k - 64);
    ull km2 = mask_for(k - 128);
    ull km3 = mask_for(k - 192);

    for (int r = 0; r < k - 1; r++) {
      ull cur = (r < 64) ? km0 : (r < 128) ? km1 : (r < 192) ? km2 : km3;
      if (!((cur >> (r & 63)) & 1ull)) continue;
      float X1 = px1[r], Y1 = py1[r], X2 = px2[r], Y2 = py2[r];
      float ar = (X2 - X1) * (Y2 - Y1);
      {
        int e = lane;
        float iw = fminf(X2, mx2[0]) - fmaxf(X1, mx1[0]);
        float ih = fminf(Y2, my2[0]) - fmaxf(Y1, my1[0]);
        iw = fmaxf(iw, 0.0f); ih = fmaxf(ih, 0.0f);
        float inter = iw * ih;
        float iou = inter / (ar + mar[0] - inter + 1e-16f);
        km0 &= ~__ballot(iou >= 0.4f && e > r && e < k);
      }
      if (k > 64) {
        int e = 64 + lane;
        float iw = fminf(X2, mx2[1]) - fmaxf(X1, mx1[1]);
        float ih = fminf(Y2, my2[1]) - fmaxf(Y1, my1[1]);
        iw = fmaxf(iw, 0.0f); ih = fmaxf(ih, 0.0f);
        float inter = iw * ih;
        float iou = inter / (ar + mar[1] - inter + 1e-16f);
        km1 &= ~__ballot(iou >= 0.4f && e > r && e < k);
      }
      if (k > 128) {
        int e = 128 + lane;
        float iw = fminf(X2, mx2[2]) - fmaxf(X1, mx1[2]);
        float ih = fminf(Y2, my2[2]) - fmaxf(Y1, my1[2]);
        iw = fmaxf(iw, 0.0f); ih = fmaxf(ih, 0.0f);
        float inter = iw * ih;
        float iou = inter / (ar + mar[2] - inter + 1e-16f);
        km2 &= ~__ballot(iou >= 0.4f && e > r && e < k);
      }
      if (k > 192) {
        int e = 192 + lane;
        float iw = fminf(X2, mx2[3]) - fmaxf(X1, mx1[3]);
        float ih = fminf(Y2, my2[3]) - fmaxf(Y1, my1[3]);
        iw = fmaxf(iw, 0.0f); ih = fmaxf(ih, 0.0f);
        float inter = iw * ih;
        float iou = inter / (ar + mar[3] - inter + 1e-16f);
        km3 &= ~__ballot(iou >= 0.4f && e > r && e < k);
      }
    }

#pragma unroll
    for (int s = 0; s < 4; s++) {
      ull kms = (s == 0) ? km0 : (s == 1) ? km1 : (s == 2) ? km2 : km3;
      int e = s * 64 + lane;
      if (e < k) {
        float4 a, b4;
        if ((kms >> lane) & 1ull) {
          a  = make_float4((float)img, mx1[s], my1[s], mx2[s]);
          b4 = make_float4(my2[s], mob[s], mmx[s], (float)cls);
        } else {
          a  = make_float4(0.f, 0.f, 0.f, 0.f);
          b4 = a;
        }
        float4* o = (float4*)(ob + (long)mbi[s] * 8);
        o[0] = a; o[1] = b4;
      }
    }
  }
}

extern "C" void kernel_launch(void* const* d_in, const int* in_sizes, int n_in,
                              void* d_out, int out_size, void* d_ws, size_t ws_size,
                              hipStream_t stream) {
  const float* x = (const float*)d_in[0];
  float* out = (float*)d_out;
  nms_fused<<<BSZ * NCLS, TPB, 0, stream>>>(x, out);
}

// Round 7
// 72.413 us; speedup vs baseline: 1.6080x; 1.6080x over previous
//
#include <hip/hip_runtime.h>

#define BSZ   2
#define NBOX  6300
#define NATTR 85
#define NCLS  80
#define CAP   256      // per-(img,class) cap; count ~ Binom(6300,1/160): mean 39, sd 6.3
#define NWIN  99       // ceil(NBOX/64) 64-box windows per image
#define PBLK  (BSZ * NWIN)   // 198 producer blocks (dispatched first)
#define CBLK  (BSZ * NCLS)   // 160 consumer blocks
#define TPB   1024

typedef unsigned long long ull;
typedef unsigned int u32;

#define RLX __ATOMIC_RELAXED
#define AGT __HIP_MEMORY_SCOPE_AGENT

static __device__ __forceinline__ ull mask_for(int rem) {
  if (rem <= 0) return 0ull;
  if (rem >= 64) return ~0ull;
  return (1ull << rem) - 1ull;
}

// Self-validating tags (upper 32 bits of each channel word). ws is poisoned
// with a constant dword pattern between replays; a poison word validates only
// if that pattern equals one specific hashed tag. R6 ran with this scheme and
// showed no tag-validation artifacts (its failure was a write-write race).
static __device__ __forceinline__ u32 tagM(int idx) {
  return 0x5AB00000u ^ ((u32)idx * 0x85EBCA6Bu);
}
static __device__ __forceinline__ u32 tagD(int idx) {
  return 0x3D700000u ^ ((u32)idx * 0x9E3779B9u);
}
static __device__ __forceinline__ ull pk(u32 tag, u32 pay) {
  return ((ull)tag << 32) | (ull)pay;
}

// ONE kernel, producer/consumer dataflow (no barrier/fence/L2 flush).
//
// R6 POST-MORTEM (absmax 79 = lost zero-write): producer wrote real rows for
// valid boxes and the consumer re-wrote the SAME BYTES with zeros for
// suppressed ones -- two dirty copies in two non-coherent XCD L2s, write-back
// order undefined. FIX: single-writer-per-byte discipline.
//   * producer writes out rows ONLY for invalid boxes (zeros), and publishes
//     each valid box's record (x1,y1,x2,y2,obj,maxscore) as 6 tagged chD words
//     + per-(window,class) candidate bitmask as 2 tagged chM words.
//   * consumer (img,cls) writes ALL rows of its candidates: kept -> real row,
//     suppressed -> zero row. Every out row has exactly one writer.
// Cross-XCD sharing of a cache LINE at different bytes is safe (byte-masked
// merge -- empirically proven by R2/R4/R5's adjacent-row multi-XCD writes).
//
// Ordering: producer __syncthreads drains vmcnt(0), so chD stores complete
// before chM mask stores issue; per-word chD tag spins are belt-and-suspenders.
// Deadlock-free: producers (blockIdx 0..197) never wait; only consumers spin
// (358 blocks x 1024 thr, 2 blocks/CU -> all co-resident anyway).
//
// Semantics per box (R0/R2/R4-verified): conf = obj>0.5; cls_idx = argmax of
// conf-masked scores (first-index tiebreak); valid = conf && max>0.3. Greedy
// per-class NMS, rank = (obj desc, box idx asc) == exact ref order.
__global__ __launch_bounds__(TPB) void nms_df(
    const float* __restrict__ x,
    float* __restrict__ out,
    ull* __restrict__ chM,     // [2][NWIN][NCLS][2] tagged mask halves
    ull* __restrict__ chD) {   // [2*NBOX][6] tagged per-box records
  int t    = threadIdx.x;
  int lane = t & 63;
  int wv   = t >> 6;
  int bid  = blockIdx.x;

  if (bid < PBLK) {
    // ========================= producer =========================
    __shared__ ull lmask[NCLS];
    if (t < NCLS) lmask[t] = 0;
    __syncthreads();

    int img = bid / NWIN, w = bid - img * NWIN;
    int base_box = w * 64;
    int nb = NBOX - base_box; if (nb > 64) nb = 64;   // window 98 has 28

#pragma unroll
    for (int i = 0; i < 4; i++) {        // 16 waves x 4 rounds = 64 boxes
      int lb = wv + 16 * i;
      if (lb < nb) {
        int box = img * NBOX + base_box + lb;
        const float* p = x + (long)box * NATTR;
        float r0 = p[lane];                                    // attrs 0..63
        float r1 = (lane < NATTR - 64) ? p[64 + lane] : -1.0f; // attrs 64..84

        float c0 = (lane >= 5) ? r0 : -1.0f;
        float v; int vi;
        if (r1 > c0) { v = r1; vi = 64 + lane; }   // equal -> lower index
        else         { v = c0; vi = lane; }
        for (int off = 32; off > 0; off >>= 1) {   // butterfly max-argmax
          float ov = __shfl_xor(v, off);
          int   oi = __shfl_xor(vi, off);
          if (ov > v || (ov == v && oi < vi)) { v = ov; vi = oi; }
        }

        float cx  = __shfl(r0, 0), cy = __shfl(r0, 1);
        float ww  = __shfl(r0, 2), hh = __shfl(r0, 3);
        float obj = __shfl(r0, 4);
        bool valid = (obj > 0.5f) && (v > 0.3f);
        int  cls   = vi - 5;

        if (lane == 0) {
          if (valid) {
            // publish record; do NOT touch the out row (consumer owns it)
            float hw = ww * 0.5f, hh2 = hh * 0.5f;  // exact halving; fma-safe
            float X1 = cx - hw, Y1 = cy - hh2, X2 = cx + hw, Y2 = cy + hh2;
            int g6 = box * 6;
            __hip_atomic_store(&chD[g6+0], pk(tagD(g6+0), __float_as_uint(X1)),  RLX, AGT);
            __hip_atomic_store(&chD[g6+1], pk(tagD(g6+1), __float_as_uint(Y1)),  RLX, AGT);
            __hip_atomic_store(&chD[g6+2], pk(tagD(g6+2), __float_as_uint(X2)),  RLX, AGT);
            __hip_atomic_store(&chD[g6+3], pk(tagD(g6+3), __float_as_uint(Y2)),  RLX, AGT);
            __hip_atomic_store(&chD[g6+4], pk(tagD(g6+4), __float_as_uint(obj)), RLX, AGT);
            __hip_atomic_store(&chD[g6+5], pk(tagD(g6+5), __float_as_uint(v)),   RLX, AGT);
            atomicOr(&lmask[cls], 1ull << lb);
          } else {
            // invalid box: producer is the unique writer of this row
            float4 z = make_float4(0.f, 0.f, 0.f, 0.f);
            float4* o = (float4*)(out + (long)box * 8);
            o[0] = z; o[1] = z;
          }
        }
      }
    }
    __syncthreads();   // drains vmcnt(0): chD stores complete before masks
    if (t < NCLS * 2) {
      int c = t >> 1, h = t & 1;
      int idx = ((img * NWIN + w) * NCLS + c) * 2 + h;
      u32 half = (u32)(lmask[c] >> (h * 32));
      __hip_atomic_store(&chM[idx], pk(tagM(idx), half), RLX, AGT);
    }
    return;
  }

  // ========================= consumer =========================
  int cc  = bid - PBLK;
  int img = cc / NCLS, cls = cc - img * NCLS;

  __shared__ u32  shalf[NWIN][2];
  __shared__ ull  wm[NWIN];
  __shared__ int  sbi[CAP];
  __shared__ int  nbad, skS;
  // fallback-only (k > 64)
  __shared__ float ssc[CAP];
  __shared__ float px1[CAP], py1[CAP], px2[CAP], py2[CAP];
  __shared__ float pmx[CAP];
  __shared__ int   pbi[CAP];

  // ---- poll this class's 198 tagged mask words ----
  int  w_ = t >> 1, h_ = t & 1;
  int  idx_ = ((img * NWIN + w_) * NCLS + cls) * 2 + h_;
  u32  mytag = tagM(idx_);
  bool have = (t >= NWIN * 2);
  for (;;) {
    if (t == 0) nbad = 0;
    __syncthreads();
    if (!have) {
      ull d = __hip_atomic_load(&chM[idx_], RLX, AGT);
      if ((u32)(d >> 32) == mytag) { shalf[w_][h_] = (u32)d; have = true; }
      else atomicAdd(&nbad, 1);
    }
    __syncthreads();
    if (nbad == 0) break;
    __builtin_amdgcn_s_sleep(16);
  }
  if (t < NWIN) wm[t] = ((ull)shalf[t][1] << 32) | shalf[t][0];
  __syncthreads();

  // ---- compact bitmask -> ordered candidate list (box idx ascending) ----
  if (wv == 0) {
    ull m0 = (lane < NWIN)      ? wm[lane]      : 0ull;
    ull m1 = (64 + lane < NWIN) ? wm[64 + lane] : 0ull;
    int e0 = __popcll(m0), e1 = __popcll(m1);
    int s0 = e0;
    for (int o = 1; o < 64; o <<= 1) { int u = __shfl_up(s0, o); if (lane >= o) s0 += u; }
    int tot0 = __shfl(s0, 63);
    int s1 = e1;
    for (int o = 1; o < 64; o <<= 1) { int u = __shfl_up(s1, o); if (lane >= o) s1 += u; }
    int tot1 = __shfl(s1, 63);
    int b0 = s0 - e0;
    int b1 = tot0 + s1 - e1;
    while (m0) { int b = __builtin_ctzll(m0); m0 &= m0 - 1;
                 if (b0 < CAP) sbi[b0] = lane * 64 + b; b0++; }
    while (m1) { int b = __builtin_ctzll(m1); m1 &= m1 - 1;
                 if (b1 < CAP) sbi[b1] = (64 + lane) * 64 + b; b1++; }
    if (lane == 0) { int kk = tot0 + tot1; skS = kk < CAP ? kk : CAP; }
  }
  __syncthreads();
  int k = skS;
  if (k == 0) return;                  // no candidates -> no rows owned

  float* ob = out + (long)img * NBOX * 8;

  if (k <= 64) {
    // ================== register fast path (wave 0 only) ==================
    if (wv == 0) {
      int j = lane;
      float x1 = 0.f, y1 = 0.f, x2 = 0.f, y2 = 0.f, sc = 0.f, mx = 0.f;
      int bi = 0;
      if (j < k) {
        bi = sbi[j];
        int g6 = (img * NBOX + bi) * 6;
        u32 vv[6];
#pragma unroll
        for (int q = 0; q < 6; q++) {
          ull d = __hip_atomic_load(&chD[g6 + q], RLX, AGT);
          while ((u32)(d >> 32) != tagD(g6 + q)) {     // ~never taken
            __builtin_amdgcn_s_sleep(2);
            d = __hip_atomic_load(&chD[g6 + q], RLX, AGT);
          }
          vv[q] = (u32)d;
        }
        x1 = __uint_as_float(vv[0]); y1 = __uint_as_float(vv[1]);
        x2 = __uint_as_float(vv[2]); y2 = __uint_as_float(vv[3]);
        sc = __uint_as_float(vv[4]); mx = __uint_as_float(vv[5]);
      }
      // rank = stable argsort(-obj, tiebreak: box index asc). All 64 lanes
      // run the loop; j>=k lanes get identity rank j (sc=0 there).
      int rank = 0;
      for (int i = 0; i < k; i++) {
        float si  = __shfl(sc, i);
        int   bii = __shfl(bi, i);
        rank += (si > sc) || (si == sc && bii < bi);
      }
      if (j >= k) rank = j;

      // scatter to rank order: after this, lane index == rank.
      int r4 = rank << 2;
      x1 = __int_as_float(__builtin_amdgcn_ds_permute(r4, __float_as_int(x1)));
      y1 = __int_as_float(__builtin_amdgcn_ds_permute(r4, __float_as_int(y1)));
      x2 = __int_as_float(__builtin_amdgcn_ds_permute(r4, __float_as_int(x2)));
      y2 = __int_as_float(__builtin_amdgcn_ds_permute(r4, __float_as_int(y2)));
      sc = __int_as_float(__builtin_amdgcn_ds_permute(r4, __float_as_int(sc)));
      mx = __int_as_float(__builtin_amdgcn_ds_permute(r4, __float_as_int(mx)));
      bi = __builtin_amdgcn_ds_permute(r4, bi);

      float ar = (x2 - x1) * (y2 - y1);   // ref area expression

      // greedy: kept rank r suppresses later ranks with IoU >= 0.4
      ull keep = mask_for(k);
      for (int r = 0; r < k - 1; r++) {
        if (!((keep >> r) & 1ull)) continue;   // uniform skip
        float X1 = __shfl(x1, r), Y1 = __shfl(y1, r);
        float X2 = __shfl(x2, r), Y2 = __shfl(y2, r);
        float AR = __shfl(ar, r);
        float iw = fminf(X2, x2) - fmaxf(X1, x1);
        float ih = fminf(Y2, y2) - fmaxf(Y1, y1);
        iw = fmaxf(iw, 0.0f); ih = fmaxf(ih, 0.0f);
        float inter = iw * ih;
        float iou = inter / (AR + ar - inter + 1e-16f);  // ref assoc + eps
        keep &= ~__ballot(iou >= 0.4f && lane > r);
      }

      // consumer is the UNIQUE writer of every candidate row
      if (lane < k) {
        float4 a, b4;
        if ((keep >> lane) & 1ull) {
          a  = make_float4((float)img, x1, y1, x2);
          b4 = make_float4(y2, sc, mx, (float)cls);
        } else {
          a  = make_float4(0.f, 0.f, 0.f, 0.f);
          b4 = a;
        }
        float4* o = (float4*)(ob + (long)bi * 8);
        o[0] = a; o[1] = b4;
      }
    }
    return;
  }

  // ====================== generic LDS fallback (k > 64) ======================
  {
    float bx1 = 0, by1 = 0, bx2 = 0, by2 = 0, bob = 0, bmx = 0;
    int   bidx = 0;
    if (t < k) {
      bidx = sbi[t];
      int g6 = (img * NBOX + bidx) * 6;
      u32 vv[6];
#pragma unroll
      for (int q = 0; q < 6; q++) {
        ull d = __hip_atomic_load(&chD[g6 + q], RLX, AGT);
        while ((u32)(d >> 32) != tagD(g6 + q)) {
          __builtin_amdgcn_s_sleep(2);
          d = __hip_atomic_load(&chD[g6 + q], RLX, AGT);
        }
        vv[q] = (u32)d;
      }
      bx1 = __uint_as_float(vv[0]); by1 = __uint_as_float(vv[1]);
      bx2 = __uint_as_float(vv[2]); by2 = __uint_as_float(vv[3]);
      bob = __uint_as_float(vv[4]); bmx = __uint_as_float(vv[5]);
      ssc[t] = bob;
    }
    __syncthreads();

    if (t < k) {
      int rank = 0;
      for (int j2 = 0; j2 < k; j2++) {
        float sj = ssc[j2];
        rank += (sj > bob) || (sj == bob && sbi[j2] < bidx);
      }
      px1[rank] = bx1; py1[rank] = by1;
      px2[rank] = bx2; py2[rank] = by2;
      pmx[rank] = bmx; pbi[rank] = bidx;
    }
    __syncthreads();
    if (t < k) ssc[t] = 0.f;           // reuse ssc for rank-ordered obj
    __syncthreads();
    if (t < k) {
      // recompute obj into rank order via gather (pbi gives original sbi val)
      // simpler: store obj alongside during scatter -- do it now from px/py?
      // obj was bob at original t; scatter it like the others:
    }
    // (scatter obj with a second pass to keep code simple)
    if (t < k) {
      int rank = 0;
      for (int j2 = 0; j2 < k; j2++) {
        float sj = ssc[j2];  // ssc zeroed; recompute rank from pbi instead
      }
    }
    // NOTE: obj in rank order = descending; reconstruct from comparisons is
    // overkill -- carry it: redo scatter including obj.
    __syncthreads();
    if (t < k) {
      // redo full scatter including obj (cheap, k<=256)
      bidx = sbi[t];
      int g6 = (img * NBOX + bidx) * 6;
      bob = __uint_as_float((u32)__hip_atomic_load(&chD[g6 + 4], RLX, AGT));
      int rank = 0;
      for (int j2 = 0; j2 < k; j2++) {
        float sj = __uint_as_float((u32)__hip_atomic_load(
            &chD[(img * NBOX + sbi[j2]) * 6 + 4], RLX, AGT));
        rank += (sj > bob) || (sj == bob && sbi[j2] < bidx);
      }
      ssc[rank] = bob;
    }
    __syncthreads();

    if (wv == 0) {
      float mx1[4], my1[4], mx2[4], my2[4], mar[4], mob[4], mmx[4];
      int   mbi[4];
#pragma unroll
      for (int s = 0; s < 4; s++) {
        int e = s * 64 + lane;
        if (e < k) {
          mx1[s] = px1[e]; my1[s] = py1[e];
          mx2[s] = px2[e]; my2[s] = py2[e];
          mob[s] = ssc[e]; mmx[s] = pmx[e];
          mbi[s] = pbi[e];
          mar[s] = (mx2[s] - mx1[s]) * (my2[s] - my1[s]);
        } else {
          mx1[s] = 0; my1[s] = 0; mx2[s] = 0; my2[s] = 0;
          mar[s] = 0; mob[s] = 0; mmx[s] = 0; mbi[s] = 0;
        }
      }
      ull km0 = mask_for(k);
      ull km1 = mask_for(k - 64);
      ull km2 = mask_for(k - 128);
      ull km3 = mask_for(k - 192);

      for (int r = 0; r < k - 1; r++) {
        ull cur = (r < 64) ? km0 : (r < 128) ? km1 : (r < 192) ? km2 : km3;
        if (!((cur >> (r & 63)) & 1ull)) continue;
        float X1 = px1[r], Y1 = py1[r], X2 = px2[r], Y2 = py2[r];
        float ar = (X2 - X1) * (Y2 - Y1);
        {
          int e = lane;
          float iw = fminf(X2, mx2[0]) - fmaxf(X1, mx1[0]);
          float ih = fminf(Y2, my2[0]) - fmaxf(Y1, my1[0]);
          iw = fmaxf(iw, 0.0f); ih = fmaxf(ih, 0.0f);
          float inter = iw * ih;
          float iou = inter / (ar + mar[0] - inter + 1e-16f);
          km0 &= ~__ballot(iou >= 0.4f && e > r && e < k);
        }
        if (k > 64) {
          int e = 64 + lane;
          float iw = fminf(X2, mx2[1]) - fmaxf(X1, mx1[1]);
          float ih = fminf(Y2, my2[1]) - fmaxf(Y1, my1[1]);
          iw = fmaxf(iw, 0.0f); ih = fmaxf(ih, 0.0f);
          float inter = iw * ih;
          float iou = inter / (ar + mar[1] - inter + 1e-16f);
          km1 &= ~__ballot(iou >= 0.4f && e > r && e < k);
        }
        if (k > 128) {
          int e = 128 + lane;
          float iw = fminf(X2, mx2[2]) - fmaxf(X1, mx1[2]);
          float ih = fminf(Y2, my2[2]) - fmaxf(Y1, my1[2]);
          iw = fmaxf(iw, 0.0f); ih = fmaxf(ih, 0.0f);
          float inter = iw * ih;
          float iou = inter / (ar + mar[2] - inter + 1e-16f);
          km2 &= ~__ballot(iou >= 0.4f && e > r && e < k);
        }
        if (k > 192) {
          int e = 192 + lane;
          float iw = fminf(X2, mx2[3]) - fmaxf(X1, mx1[3]);
          float ih = fminf(Y2, my2[3]) - fmaxf(Y1, my1[3]);
          iw = fmaxf(iw, 0.0f); ih = fmaxf(ih, 0.0f);
          float inter = iw * ih;
          float iou = inter / (ar + mar[3] - inter + 1e-16f);
          km3 &= ~__ballot(iou >= 0.4f && e > r && e < k);
        }
      }

#pragma unroll
      for (int s = 0; s < 4; s++) {
        ull kms = (s == 0) ? km0 : (s == 1) ? km1 : (s == 2) ? km2 : km3;
        int e = s * 64 + lane;
        if (e < k) {
          float4 a, b4;
          if ((kms >> lane) & 1ull) {
            a  = make_float4((float)img, mx1[s], my1[s], mx2[s]);
            b4 = make_float4(my2[s], mob[s], mmx[s], (float)cls);
          } else {
            a  = make_float4(0.f, 0.f, 0.f, 0.f);
            b4 = a;
          }
          float4* o = (float4*)(ob + (long)mbi[s] * 8);
          o[0] = a; o[1] = b4;
        }
      }
    }
  }
}

extern "C" void kernel_launch(void* const* d_in, const int* in_sizes, int n_in,
                              void* d_out, int out_size, void* d_ws, size_t ws_size,
                              hipStream_t stream) {
  const float* x = (const float*)d_in[0];
  float* out = (float*)d_out;
  ull* chM = (ull*)d_ws;                           // 2*99*80*2 ulls = 253,440 B
  ull* chD = (ull*)((char*)d_ws + (1 << 18));      // 12600*6 ulls  = 604,800 B

  nms_df<<<PBLK + CBLK, TPB, 0, stream>>>(x, out, chM, chD);
}

// Round 8
// 70.426 us; speedup vs baseline: 1.6533x; 1.0282x over previous
//
#include <hip/hip_runtime.h>

#define BSZ   2
#define NBOX  6300
#define NATTR 85
#define NCLS  80
#define CAP   256      // per-(img,class) cap; count ~ Binom(6300,1/160): mean 39, sd 6.3
#define NWIN  99       // ceil(NBOX/64) 64-box windows per image
#define PBLK  (BSZ * NWIN)   // 198 prep blocks (one per window)
#define PTPB  1024           // 16 waves: 4 rounds x 16 = 64 boxes/window
#define NTPB  256            // nms kernel threads

typedef unsigned long long ull;

static __device__ __forceinline__ ull mask_for(int rem) {
  if (rem <= 0) return 0ull;
  if (rem >= 64) return ~0ull;
  return (1ull << rem) - 1ull;
}

// Two kernels — the kernel boundary is the cheapest device-scope sync on this
// chip (~13 us; measured ledger: cg grid.sync 65, custom barrier 43, tagged
// LLC dataflow 17, redundant-scan designs +53..86 device). Structure = R4
// (68.6 us) with the scan replaced by bitmask compaction:
//   prep (R7-verified window-per-block producer): writes FINAL out rows
//     (real if valid, zeros otherwise) + per-(img,cls,window) candidate
//     bitmasks as plain ull stores. chM needs no init: every word is written
//     by exactly one block before kernel 2 reads it (boundary-ordered).
//   nms: loads its class's 99 contiguous mask words (13 cache lines vs the
//     old 6300-int scan), wave-0 popc/prefix/ctz compaction (R7-verified) ->
//     candidate list, then R4-verified greedy NMS; zeroes suppressed rows only.
//
// Semantics per box (R0/R4-verified): conf = obj>0.5; cls_idx = argmax of
// conf-masked scores (first-index tiebreak; jnp.argmax); valid = conf &&
// max>0.3. Per-class greedy NMS == ref's global greedy loop (suppression
// requires same_cls; invalid boxes never act); rank = (obj desc, box asc).

__global__ __launch_bounds__(PTPB) void prep_kernel(
    const float* __restrict__ x,
    float* __restrict__ out,
    ull* __restrict__ chM) {   // [BSZ][NCLS][NWIN] candidate bitmasks
  __shared__ ull lmask[NCLS];
  int t    = threadIdx.x;
  int lane = t & 63;
  int wv   = t >> 6;
  int bid  = blockIdx.x;

  if (t < NCLS) lmask[t] = 0;
  __syncthreads();

  int img = bid / NWIN, w = bid - img * NWIN;
  int base_box = w * 64;
  int nb = NBOX - base_box; if (nb > 64) nb = 64;   // window 98 has 28

#pragma unroll
  for (int i = 0; i < 4; i++) {        // 16 waves x 4 rounds = 64 boxes
    int lb = wv + 16 * i;
    if (lb < nb) {
      int box = img * NBOX + base_box + lb;
      const float* p = x + (long)box * NATTR;
      float r0 = p[lane];                                    // attrs 0..63
      float r1 = (lane < NATTR - 64) ? p[64 + lane] : -1.0f; // attrs 64..84

      float c0 = (lane >= 5) ? r0 : -1.0f;
      float v; int vi;
      if (r1 > c0) { v = r1; vi = 64 + lane; }   // equal -> keep lower index
      else         { v = c0; vi = lane; }
      for (int off = 32; off > 0; off >>= 1) {   // butterfly max-argmax
        float ov = __shfl_xor(v, off);
        int   oi = __shfl_xor(vi, off);
        if (ov > v || (ov == v && oi < vi)) { v = ov; vi = oi; }
      }

      float cx  = __shfl(r0, 0), cy = __shfl(r0, 1);
      float ww  = __shfl(r0, 2), hh = __shfl(r0, 3);
      float obj = __shfl(r0, 4);
      bool valid = (obj > 0.5f) && (v > 0.3f);
      int  cls   = vi - 5;

      if (lane == 0) {
        float4 a, b;
        if (valid) {
          float hw = ww * 0.5f, hh2 = hh * 0.5f;  // exact halving; fma-safe
          a = make_float4((float)img, cx - hw, cy - hh2, cx + hw);
          b = make_float4(cy + hh2, obj, v, (float)cls);
          atomicOr(&lmask[cls], 1ull << lb);      // LDS atomic
        } else {
          a = make_float4(0.f, 0.f, 0.f, 0.f);
          b = a;
        }
        float4* o = (float4*)(out + (long)box * 8);
        o[0] = a; o[1] = b;
      }
    }
  }
  __syncthreads();
  // [img][cls][win] layout: kernel-2 reads 99 contiguous ulls per (img,cls)
  if (t < NCLS) chM[((long)img * NCLS + t) * NWIN + w] = lmask[t];
}

__global__ __launch_bounds__(NTPB) void nms_kernel(
    const ull* __restrict__ chM,
    float* out) {
  __shared__ ull  wm[NWIN];
  __shared__ int  sbi[CAP];
  __shared__ int  skS;
  // fallback-only arrays (k > 64)
  __shared__ float ssc[CAP];
  __shared__ float px1[CAP], py1[CAP], px2[CAP], py2[CAP];
  __shared__ int   pbi[CAP];

  int bc   = blockIdx.x;
  int img  = bc / NCLS;
  int cls  = bc - img * NCLS;
  int t    = threadIdx.x;
  int lane = t & 63;
  int w    = t >> 6;

  if (t < NWIN) wm[t] = chM[((long)img * NCLS + cls) * NWIN + t];
  __syncthreads();

  // ---- compact bitmask -> candidate list, box idx ascending (R7-verified) --
  if (w == 0) {
    ull m0 = (lane < NWIN)      ? wm[lane]      : 0ull;
    ull m1 = (64 + lane < NWIN) ? wm[64 + lane] : 0ull;
    int e0 = __popcll(m0), e1 = __popcll(m1);
    int s0 = e0;
    for (int o = 1; o < 64; o <<= 1) { int u = __shfl_up(s0, o); if (lane >= o) s0 += u; }
    int tot0 = __shfl(s0, 63);
    int s1 = e1;
    for (int o = 1; o < 64; o <<= 1) { int u = __shfl_up(s1, o); if (lane >= o) s1 += u; }
    int tot1 = __shfl(s1, 63);
    int b0 = s0 - e0;
    int b1 = tot0 + s1 - e1;
    while (m0) { int b = __builtin_ctzll(m0); m0 &= m0 - 1;
                 if (b0 < CAP) sbi[b0] = lane * 64 + b; b0++; }
    while (m1) { int b = __builtin_ctzll(m1); m1 &= m1 - 1;
                 if (b1 < CAP) sbi[b1] = (64 + lane) * 64 + b; b1++; }
    if (lane == 0) { int kk = tot0 + tot1; skS = kk < CAP ? kk : CAP; }
  }
  __syncthreads();
  int k = skS;
  if (k == 0) return;                  // uniform

  if (k <= 64) {
    // ================== register fast path (wave 0 only) ==================
    if (w == 0) {
      int j = lane;
      float x1 = 0.f, y1 = 0.f, x2 = 0.f, y2 = 0.f, sc = 0.f;
      int bi = 0;
      if (j < k) {
        bi = sbi[j];
        const float4* o = (const float4*)(out + ((long)img * NBOX + bi) * 8);
        float4 a = o[0], b = o[1];
        x1 = a.y; y1 = a.z; x2 = a.w; y2 = b.x; sc = b.y;
      }
      // rank = stable argsort(-obj, tiebreak: box index asc). All 64 lanes
      // run the loop (no divergence); j>=k lanes get identity rank j.
      int rank = 0;
      for (int i = 0; i < k; i++) {
        float si  = __shfl(sc, i);
        int   bii = __shfl(bi, i);
        rank += (si > sc) || (si == sc && bii < bi);
      }
      if (j >= k) rank = j;

      // scatter to rank order: after this, lane index == rank.
      int r4 = rank << 2;
      x1 = __int_as_float(__builtin_amdgcn_ds_permute(r4, __float_as_int(x1)));
      y1 = __int_as_float(__builtin_amdgcn_ds_permute(r4, __float_as_int(y1)));
      x2 = __int_as_float(__builtin_amdgcn_ds_permute(r4, __float_as_int(x2)));
      y2 = __int_as_float(__builtin_amdgcn_ds_permute(r4, __float_as_int(y2)));
      bi = __builtin_amdgcn_ds_permute(r4, bi);

      float ar = (x2 - x1) * (y2 - y1);   // ref area expression

      // greedy: kept rank r suppresses later ranks with IoU >= 0.4
      ull keep = mask_for(k);
      for (int r = 0; r < k - 1; r++) {
        if (!((keep >> r) & 1ull)) continue;   // uniform skip
        float X1 = __shfl(x1, r), Y1 = __shfl(y1, r);
        float X2 = __shfl(x2, r), Y2 = __shfl(y2, r);
        float AR = __shfl(ar, r);
        float iw = fminf(X2, x2) - fmaxf(X1, x1);
        float ih = fminf(Y2, y2) - fmaxf(Y1, y1);
        iw = fmaxf(iw, 0.0f); ih = fmaxf(ih, 0.0f);
        float inter = iw * ih;
        float iou = inter / (AR + ar - inter + 1e-16f);  // ref assoc + eps
        keep &= ~__ballot(iou >= 0.4f && lane > r);
      }

      // zero only the suppressed rows (kept rows already final from prep)
      if (lane < k && !((keep >> lane) & 1ull)) {
        float4 z = make_float4(0.f, 0.f, 0.f, 0.f);
        float4* o = (float4*)(out + ((long)img * NBOX + bi) * 8);
        o[0] = z; o[1] = z;
      }
    }
    return;
  }

  // ====================== generic LDS fallback (k > 64) ======================
  float bx1 = 0, by1 = 0, bx2 = 0, by2 = 0, bobj = 0;
  int   bidx = 0;
  if (t < k) {
    bidx = sbi[t];
    const float4* o = (const float4*)(out + ((long)img * NBOX + bidx) * 8);
    float4 a = o[0], b = o[1];
    bx1 = a.y; by1 = a.z; bx2 = a.w; by2 = b.x; bobj = b.y;
    ssc[t] = bobj;
  }
  __syncthreads();

  if (t < k) {
    int rank = 0;
    for (int j = 0; j < k; j++) {
      float sj = ssc[j];
      rank += (sj > bobj) || (sj == bobj && sbi[j] < bidx);
    }
    px1[rank] = bx1; py1[rank] = by1;
    px2[rank] = bx2; py2[rank] = by2;
    pbi[rank] = bidx;
  }
  __syncthreads();

  if (w == 0) {
    float mx1[4], my1[4], mx2[4], my2[4], mar[4];
    int   mbi[4];
#pragma unroll
    for (int s = 0; s < 4; s++) {
      int e = s * 64 + lane;
      if (e < k) {
        mx1[s] = px1[e]; my1[s] = py1[e];
        mx2[s] = px2[e]; my2[s] = py2[e];
        mbi[s] = pbi[e];
        mar[s] = (mx2[s] - mx1[s]) * (my2[s] - my1[s]);
      } else {
        mx1[s] = 0; my1[s] = 0; mx2[s] = 0; my2[s] = 0; mar[s] = 0; mbi[s] = 0;
      }
    }
    ull km0 = mask_for(k);
    ull km1 = mask_for(k - 64);
    ull km2 = mask_for(k - 128);
    ull km3 = mask_for(k - 192);

    for (int r = 0; r < k - 1; r++) {
      ull cur = (r < 64) ? km0 : (r < 128) ? km1 : (r < 192) ? km2 : km3;
      if (!((cur >> (r & 63)) & 1ull)) continue;
      float X1 = px1[r], Y1 = py1[r], X2 = px2[r], Y2 = py2[r];
      float ar = (X2 - X1) * (Y2 - Y1);
      {
        int e = lane;
        float iw = fminf(X2, mx2[0]) - fmaxf(X1, mx1[0]);
        float ih = fminf(Y2, my2[0]) - fmaxf(Y1, my1[0]);
        iw = fmaxf(iw, 0.0f); ih = fmaxf(ih, 0.0f);
        float inter = iw * ih;
        float iou = inter / (ar + mar[0] - inter + 1e-16f);
        km0 &= ~__ballot(iou >= 0.4f && e > r && e < k);
      }
      if (k > 64) {
        int e = 64 + lane;
        float iw = fminf(X2, mx2[1]) - fmaxf(X1, mx1[1]);
        float ih = fminf(Y2, my2[1]) - fmaxf(Y1, my1[1]);
        iw = fmaxf(iw, 0.0f); ih = fmaxf(ih, 0.0f);
        float inter = iw * ih;
        float iou = inter / (ar + mar[1] - inter + 1e-16f);
        km1 &= ~__ballot(iou >= 0.4f && e > r && e < k);
      }
      if (k > 128) {
        int e = 128 + lane;
        float iw = fminf(X2, mx2[2]) - fmaxf(X1, mx1[2]);
        float ih = fminf(Y2, my2[2]) - fmaxf(Y1, my1[2]);
        iw = fmaxf(iw, 0.0f); ih = fmaxf(ih, 0.0f);
        float inter = iw * ih;
        float iou = inter / (ar + mar[2] - inter + 1e-16f);
        km2 &= ~__ballot(iou >= 0.4f && e > r && e < k);
      }
      if (k > 192) {
        int e = 192 + lane;
        float iw = fminf(X2, mx2[3]) - fmaxf(X1, mx1[3]);
        float ih = fminf(Y2, my2[3]) - fmaxf(Y1, my1[3]);
        iw = fmaxf(iw, 0.0f); ih = fmaxf(ih, 0.0f);
        float inter = iw * ih;
        float iou = inter / (ar + mar[3] - inter + 1e-16f);
        km3 &= ~__ballot(iou >= 0.4f && e > r && e < k);
      }
    }

    float4 z = make_float4(0.f, 0.f, 0.f, 0.f);
#pragma unroll
    for (int s = 0; s < 4; s++) {
      ull kms = (s == 0) ? km0 : (s == 1) ? km1 : (s == 2) ? km2 : km3;
      int e = s * 64 + lane;
      if (e < k && !((kms >> lane) & 1ull)) {
        float4* o = (float4*)(out + ((long)img * NBOX + mbi[s]) * 8);
        o[0] = z; o[1] = z;
      }
    }
  }
}

extern "C" void kernel_launch(void* const* d_in, const int* in_sizes, int n_in,
                              void* d_out, int out_size, void* d_ws, size_t ws_size,
                              hipStream_t stream) {
  const float* x = (const float*)d_in[0];
  float* out = (float*)d_out;
  ull* chM = (ull*)d_ws;   // [BSZ][NCLS][NWIN] = 15840 ulls = 126,720 B

  prep_kernel<<<PBLK, PTPB, 0, stream>>>(x, out, chM);
  nms_kernel<<<BSZ * NCLS, NTPB, 0, stream>>>(chM, out);
}

// Round 9
// 69.374 us; speedup vs baseline: 1.6784x; 1.0152x over previous
//
#include <hip/hip_runtime.h>

#define BSZ   2
#define NBOX  6300
#define NATTR 85
#define NCLS  80
#define CAP   256      // per-(img,class) cap; count ~ Binom(6300,1/160): mean 39, sd 6.3
#define TPB2  512      // nms kernel threads
#define NW    8        // waves per nms block
#define CHUNK 790      // 8*790 = 6320 >= 6300 (per-wave scan chunk)
#define WCAP  128      // per-wave candidate cap (expect ~5; 128 is >>12 sigma)

typedef unsigned long long ull;

static __device__ __forceinline__ ull mask_for(int rem) {
  if (rem <= 0) return 0ull;
  if (rem >= 64) return ~0ull;
  return (1ull << rem) - 1ull;
}

// FINAL: best-measured structure (R4, 68.6 us end-to-end, absmax 0).
// Session ledger (end-to-end): cg grid.sync 138.3; custom barrier 98.2;
// redundant-scan single-kernel 107.9/116.4; tagged LLC dataflow 72.4;
// 2-kernel bitmask handoff 70.4; THIS (2-kernel vcls handoff) 68.6.
// Fixed harness costs: ~40.7 us ws-poison fill + ~8.4 us replay base +
// ~13 us second-node boundary = ~62 us; device compute ~5 us. The kernel
// boundary is the cheapest device-scope sync on gfx950's 8 non-coherent
// XCD L2s -- all in-kernel alternatives measured slower.

// Kernel 1 — one wave per box (grid exact, 12600 waves). Lanes load the 85
// attrs coalesced, butterfly-reduce max/argmax over class scores (attrs 5..84,
// first-index tiebreak = jnp.argmax). Lane 0 writes the FINAL output row
// (real row if valid, zeros otherwise) and vcls[box] = valid ? cls : -1.
__global__ __launch_bounds__(256) void prep_kernel(
    const float* __restrict__ x,
    int* __restrict__ vcls,
    float* __restrict__ out) {
  int gid  = blockIdx.x * blockDim.x + threadIdx.x;
  int box  = gid >> 6;                 // grid exact: 12600 waves
  int lane = threadIdx.x & 63;

  const float* p = x + (long)box * NATTR;
  float r0 = p[lane];                                    // attrs 0..63
  float r1 = (lane < NATTR - 64) ? p[64 + lane] : -1.0f; // attrs 64..84

  float c0 = (lane >= 5) ? r0 : -1.0f;
  float v; int vi;
  if (r1 > c0) { v = r1; vi = 64 + lane; }   // equal -> keep lower index c0
  else         { v = c0; vi = lane; }

  for (int off = 32; off > 0; off >>= 1) {   // butterfly max-argmax
    float ov = __shfl_xor(v, off);
    int   oi = __shfl_xor(vi, off);
    if (ov > v || (ov == v && oi < vi)) { v = ov; vi = oi; }
  }

  float cx  = __shfl(r0, 0), cy = __shfl(r0, 1);
  float w   = __shfl(r0, 2), h  = __shfl(r0, 3);
  float obj = __shfl(r0, 4);
  bool valid = (obj > 0.5f) && (v > 0.3f);
  int  img   = box >= NBOX ? 1 : 0;
  int  cls   = vi - 5;

  if (lane == 0) {
    vcls[box] = valid ? cls : -1;
    float4 a, b;
    if (valid) {
      float hw = w * 0.5f, hh = h * 0.5f;    // exact halving; fma-safe
      a = make_float4((float)img, cx - hw, cy - hh, cx + hw);
      b = make_float4(cy + hh, obj, v, (float)cls);
    } else {
      a = make_float4(0.f, 0.f, 0.f, 0.f);
      b = a;
    }
    float4* o = (float4*)(out + (long)box * 8);
    o[0] = a; o[1] = b;
  }
}

// Kernel 2 — one 512-thread block (8 waves) per (img, class). Per-class greedy
// NMS is exactly equivalent to the ref's global greedy loop (suppression
// requires same_cls; invalid boxes never act). Kept rows already final in out;
// this kernel only ZEROES suppressed rows. Scan: 8 waves x 790-chunk ballot
// compaction. Fast path (k<=64, always on this data): whole NMS in wave-0
// registers via shfl/ds_permute/ballot. LDS fallback for k>64.
__global__ __launch_bounds__(TPB2) void nms_kernel(
    const int* __restrict__ vcls,
    float* out) {
  __shared__ int   wlist[NW][WCAP];
  __shared__ int   wcnt[NW];
  __shared__ int   sbi[CAP];
  // fallback-only arrays (k > 64)
  __shared__ float ssc[CAP];
  __shared__ float px1[CAP], py1[CAP], px2[CAP], py2[CAP];
  __shared__ int   pbi[CAP];

  int bc   = blockIdx.x;
  int img  = bc / NCLS;
  int cls  = bc - img * NCLS;
  int t    = threadIdx.x;
  int lane = t & 63;
  int w    = t >> 6;
  const int* v = vcls + img * NBOX;

  // ---- scan: 8 waves x 790-chunk ballot compaction ----
  int base = w * CHUNK;
  int vals[13];
#pragma unroll
  for (int i = 0; i < 13; i++) {
    int local = i * 64 + lane;
    int idx   = base + local;
    vals[i] = (local < CHUNK && idx < NBOX) ? v[idx] : -1;
  }
  int cnt = 0;
  ull lt = (1ull << lane) - 1ull;
#pragma unroll
  for (int i = 0; i < 13; i++) {
    bool match = (vals[i] == cls);
    ull  m = __ballot(match);
    if (match) {
      int pos = cnt + __popcll(m & lt);
      if (pos < WCAP) wlist[w][pos] = base + i * 64 + lane;
    }
    cnt += __popcll(m);
  }
  if (lane == 0) wcnt[w] = cnt < WCAP ? cnt : WCAP;
  __syncthreads();

  int off = 0, total = 0;
  for (int j = 0; j < NW; j++) {
    int c = wcnt[j];
    if (j < w) off += c;
    total += c;
  }
  int k = total < CAP ? total : CAP;
  if (k == 0) return;                  // uniform

  for (int j = lane; j < wcnt[w]; j += 64) {
    int d = off + j;
    if (d < CAP) sbi[d] = wlist[w][j];  // ascending box-index order
  }
  __syncthreads();

  if (k <= 64) {
    // ================== register fast path (wave 0 only) ==================
    if (w == 0) {
      int j = lane;
      float x1 = 0.f, y1 = 0.f, x2 = 0.f, y2 = 0.f, sc = 0.f;
      int bi = 0;
      if (j < k) {
        bi = sbi[j];
        const float4* o = (const float4*)(out + ((long)img * NBOX + bi) * 8);
        float4 a = o[0], b = o[1];
        x1 = a.y; y1 = a.z; x2 = a.w; y2 = b.x; sc = b.y;
      }
      // rank = stable argsort(-obj, tiebreak: box index asc).
      // All 64 lanes run the loop (no divergence -> shfl well-defined);
      // j>=k lanes get identity rank j (>= k, no collision: sc=0 there).
      int rank = 0;
      for (int i = 0; i < k; i++) {
        float si  = __shfl(sc, i);
        int   bii = __shfl(bi, i);
        rank += (si > sc) || (si == sc && bii < bi);
      }
      if (j >= k) rank = j;

      // scatter to rank order: after this, lane index == rank.
      int r4 = rank << 2;
      x1 = __int_as_float(__builtin_amdgcn_ds_permute(r4, __float_as_int(x1)));
      y1 = __int_as_float(__builtin_amdgcn_ds_permute(r4, __float_as_int(y1)));
      x2 = __int_as_float(__builtin_amdgcn_ds_permute(r4, __float_as_int(x2)));
      y2 = __int_as_float(__builtin_amdgcn_ds_permute(r4, __float_as_int(y2)));
      bi = __builtin_amdgcn_ds_permute(r4, bi);

      float ar = (x2 - x1) * (y2 - y1);   // ref area expression

      // greedy: kept rank r suppresses later ranks with IoU >= 0.4
      ull keep = mask_for(k);
      for (int r = 0; r < k - 1; r++) {
        if (!((keep >> r) & 1ull)) continue;   // uniform skip
        float X1 = __shfl(x1, r), Y1 = __shfl(y1, r);
        float X2 = __shfl(x2, r), Y2 = __shfl(y2, r);
        float AR = __shfl(ar, r);
        float iw = fminf(X2, x2) - fmaxf(X1, x1);
        float ih = fminf(Y2, y2) - fmaxf(Y1, y1);
        iw = fmaxf(iw, 0.0f); ih = fmaxf(ih, 0.0f);
        float inter = iw * ih;
        float iou = inter / (AR + ar - inter + 1e-16f);  // ref assoc + eps
        keep &= ~__ballot(iou >= 0.4f && lane > r);
      }

      // zero only the suppressed rows (kept rows already final from prep)
      if (lane < k && !((keep >> lane) & 1ull)) {
        float4 z = make_float4(0.f, 0.f, 0.f, 0.f);
        float4* o = (float4*)(out + ((long)img * NBOX + bi) * 8);
        o[0] = z; o[1] = z;
      }
    }
    return;
  }

  // ====================== generic LDS fallback (k > 64) ======================
  float bx1 = 0, by1 = 0, bx2 = 0, by2 = 0, bobj = 0;
  int   bidx = 0;
  if (t < k) {
    bidx = sbi[t];
    const float4* o = (const float4*)(out + ((long)img * NBOX + bidx) * 8);
    float4 a = o[0], b = o[1];
    bx1 = a.y; by1 = a.z; bx2 = a.w; by2 = b.x; bobj = b.y;
    ssc[t] = bobj;
  }
  __syncthreads();

  if (t < k) {
    int rank = 0;
    for (int j = 0; j < k; j++) {
      float sj = ssc[j];
      rank += (sj > bobj) || (sj == bobj && sbi[j] < bidx);
    }
    px1[rank] = bx1; py1[rank] = by1;
    px2[rank] = bx2; py2[rank] = by2;
    pbi[rank] = bidx;
  }
  __syncthreads();

  if (w == 0) {
    float mx1[4], my1[4], mx2[4], my2[4], mar[4];
    int   mbi[4];
#pragma unroll
    for (int s = 0; s < 4; s++) {
      int e = s * 64 + lane;
      if (e < k) {
        mx1[s] = px1[e]; my1[s] = py1[e];
        mx2[s] = px2[e]; my2[s] = py2[e];
        mbi[s] = pbi[e];
        mar[s] = (mx2[s] - mx1[s]) * (my2[s] - my1[s]);
      } else {
        mx1[s] = 0; my1[s] = 0; mx2[s] = 0; my2[s] = 0; mar[s] = 0; mbi[s] = 0;
      }
    }
    ull km0 = mask_for(k);
    ull km1 = mask_for(k - 64);
    ull km2 = mask_for(k - 128);
    ull km3 = mask_for(k - 192);

    for (int r = 0; r < k - 1; r++) {
      ull cur = (r < 64) ? km0 : (r < 128) ? km1 : (r < 192) ? km2 : km3;
      if (!((cur >> (r & 63)) & 1ull)) continue;
      float X1 = px1[r], Y1 = py1[r], X2 = px2[r], Y2 = py2[r];
      float ar = (X2 - X1) * (Y2 - Y1);
      {
        int e = lane;
        float iw = fminf(X2, mx2[0]) - fmaxf(X1, mx1[0]);
        float ih = fminf(Y2, my2[0]) - fmaxf(Y1, my1[0]);
        iw = fmaxf(iw, 0.0f); ih = fmaxf(ih, 0.0f);
        float inter = iw * ih;
        float iou = inter / (ar + mar[0] - inter + 1e-16f);
        km0 &= ~__ballot(iou >= 0.4f && e > r && e < k);
      }
      if (k > 64) {
        int e = 64 + lane;
        float iw = fminf(X2, mx2[1]) - fmaxf(X1, mx1[1]);
        float ih = fminf(Y2, my2[1]) - fmaxf(Y1, my1[1]);
        iw = fmaxf(iw, 0.0f); ih = fmaxf(ih, 0.0f);
        float inter = iw * ih;
        float iou = inter / (ar + mar[1] - inter + 1e-16f);
        km1 &= ~__ballot(iou >= 0.4f && e > r && e < k);
      }
      if (k > 128) {
        int e = 128 + lane;
        float iw = fminf(X2, mx2[2]) - fmaxf(X1, mx1[2]);
        float ih = fminf(Y2, my2[2]) - fmaxf(Y1, my1[2]);
        iw = fmaxf(iw, 0.0f); ih = fmaxf(ih, 0.0f);
        float inter = iw * ih;
        float iou = inter / (ar + mar[2] - inter + 1e-16f);
        km2 &= ~__ballot(iou >= 0.4f && e > r && e < k);
      }
      if (k > 192) {
        int e = 192 + lane;
        float iw = fminf(X2, mx2[3]) - fmaxf(X1, mx1[3]);
        float ih = fminf(Y2, my2[3]) - fmaxf(Y1, my1[3]);
        iw = fmaxf(iw, 0.0f); ih = fmaxf(ih, 0.0f);
        float inter = iw * ih;
        float iou = inter / (ar + mar[3] - inter + 1e-16f);
        km3 &= ~__ballot(iou >= 0.4f && e > r && e < k);
      }
    }

    float4 z = make_float4(0.f, 0.f, 0.f, 0.f);
#pragma unroll
    for (int s = 0; s < 4; s++) {
      ull kms = (s == 0) ? km0 : (s == 1) ? km1 : (s == 2) ? km2 : km3;
      int e = s * 64 + lane;
      if (e < k && !((kms >> lane) & 1ull)) {
        float4* o = (float4*)(out + ((long)img * NBOX + mbi[s]) * 8);
        o[0] = z; o[1] = z;
      }
    }
  }
}

extern "C" void kernel_launch(void* const* d_in, const int* in_sizes, int n_in,
                              void* d_out, int out_size, void* d_ws, size_t ws_size,
                              hipStream_t stream) {
  const float* x = (const float*)d_in[0];
  float* out = (float*)d_out;
  int* vcls = (int*)d_ws;   // [BSZ*NBOX]

  prep_kernel<<<(BSZ * NBOX * 64) / 256, 256, 0, stream>>>(x, vcls, out);
  nms_kernel<<<BSZ * NCLS, TPB2, 0, stream>>>(vcls, out);
}